// Round 23
// baseline (18.803 us; speedup 1.0000x reference)
//
#include <hip/hip_runtime.h>

#define SN 128
#define SPK 512

constexpr float GMIN  = 0.1f;
constexpr float PFRAC = 0.3f;
constexpr float GMAX  = 1.0f;

// LDS-composed sparse patch, early plane fill (R22 base).
// Lazy decay: v(n) = C(n)*a + GMIN, C(n) = exp((ts0-ts[n])/TAU) <= 1.
// Untouched cell at snapshot r: u_r = GMIN*(1-C_r) (identical everywhere).
// Touch at n: a' = (1-PFRAC)*a + PFRAC*(GMAX-GMIN)/C(n); amplitude is
// non-decreasing over the touch prefix -> per-touch own-prefix candidates +
// max reproduce the exact final value (verified absmax 0.0, R11/R17-R22).
// Same-cell predecessors: hash-count buckets; only events in buckets with
// count>=2 are compacted (time order) and scanned (no false negatives).
//
// Key change vs R22: the 32 KB plane (uniform u_r) is stored to global RIGHT
// AFTER P2, so its HBM drain overlaps compact/amplitude/scatter. The P4-end
// __syncthreads (vmcnt(0)) guarantees the fill is committed; then only the
// ~500 touched cells are patched with plain dword stores of the tile's final
// max (benign races: all writers of a cell store the identical value).

__global__ __launch_bounds__(512, 4) void fuse_kernel(
    const int*   __restrict__ event,   // (SN, SPK, 3) int32: x, y, pol
    const float* __restrict__ ts,      // (SN, SPK) f32, ascending
    const int*   __restrict__ tt,      // (SN, SPK) int32 in [0,8)
    const int*   __restrict__ length,  // (SN,) int32
    float*       __restrict__ out)     // (SN, 8, 2, 64, 64) f32
{
    __shared__ int      tile[2 * 64 * 64];   // 32 KB; first 16 KB aliased as hcnt
    __shared__ float    stsn[SPK];
    __shared__ unsigned lpk [SPK];           // ambiguous list: (n<<16)|key
    __shared__ float    lCr [SPK];
    __shared__ int      wlast[8];            // per-wave last occurrence of slot r
    __shared__ int      wcnt [8];
    __shared__ float    sCs;                 // C_r
    __shared__ int      sNr;                 // n_r
    __shared__ int      sUb;                 // bits(u_r)

    unsigned* hcnt = (unsigned*)tile;        // 4096 buckets (dead after P2)

    const int blk  = blockIdx.x;
    const int s    = blk >> 3;
    const int r    = blk & 7;
    const int t    = threadIdx.x;            // event index n = t
    const int lane = t & 63;
    const int wid  = t >> 6;                 // 0..7

    const int   len = length[s];
    const float ts0 = ts[s * SPK];

    // issue event loads early
    const int* ev = event + (size_t)(s * SPK + t) * 3;
    const int   ex  = ev[0], ey = ev[1], ep = ev[2];
    const float tsn = ts[s * SPK + t];
    const int   tv  = tt[s * SPK + t];

    // ---- P0: init hash buckets ----
#pragma unroll
    for (int k = 0; k < 8; ++k) hcnt[t + k * 512] = 0u;
    __syncthreads();

    // ---- P1: stage + hash count + per-wave snlast ballot ----
    const bool     gate = (t < len);                    // t==0 always (len>=1)
    const unsigned key  = (unsigned)((ep << 14) | (ex << 7) | ey);
    const float    myCr = (PFRAC * (GMAX - GMIN)) * __expf(-(ts0 - tsn) * 0.01f);
    const unsigned h    = (key * 2654435761u) >> 20;    // 12-bit bucket
    stsn[t] = tsn;
    if (gate) atomicAdd(&hcnt[h], 1u);
    {
        unsigned long long m = __ballot(t >= 1 && tv == r);
        if (lane == 0)
            wlast[wid] = m ? (wid * 64 + 63 - (int)__clzll(m)) : -1;
    }
    __syncthreads();

    // ---- P2: slot table (thread 0) + ambiguity flags (all hcnt reads) ----
    if (t == 0) {
        int nr = wlast[0];
#pragma unroll
        for (int w = 1; w < 8; ++w) nr = max(nr, wlast[w]);
        if (r == 0 && nr < 0) nr = 0;                   // slot0 -> init state
        float C = 0.0f;
        if (nr >= 0) C = __expf((ts0 - stsn[nr]) * 0.01f);   // C_r <= 1
        sNr = nr;
        sCs = C;
        sUb = __float_as_int((nr >= 0) ? (GMIN - C * GMIN) : 0.0f);
    }
    const bool amb = gate && (hcnt[h] > 1u);
    const unsigned long long bm = __ballot(amb);
    if (lane == 0) wcnt[wid] = (int)__popcll(bm);
    __syncthreads();                                    // hcnt dead from here

    // ---- P2.5: EARLY plane fill (uniform u_r) -- drains under P3/P4 ----
    {
        const float u = __int_as_float(sUb);
        float4* o4 = reinterpret_cast<float4*>(out + (size_t)(s * 8 + r) * 8192);
        const float4 f4 = make_float4(u, u, u, u);
#pragma unroll
        for (int k = 0; k < 4; ++k) o4[t + k * 512] = f4;
    }

    // ---- P3: compact ambiguous (time order) + tile zero ----
    int base = 0, nA = 0;
#pragma unroll
    for (int w = 0; w < 8; ++w) {
        int c = wcnt[w];
        if (w < wid) base += c;
        nA += c;
    }
    if (amb) {
        int pos = base + (int)__popcll(bm & ((1ull << lane) - 1ull));
        lpk[pos] = ((unsigned)t << 16) | key;
        lCr[pos] = myCr;
    }
    const int   nr  = sNr;
    const float C_r = sCs;
    {
        int4 z4; z4.x = z4.y = z4.z = z4.w = 0;         // 0 <= all candidates
        int4* T = (int4*)tile;
#pragma unroll
        for (int k = 0; k < 4; ++k) T[t + k * 512] = z4;
    }
    __syncthreads();                                    // tile + lpk/lCr ready

    // ---- P4: own-prefix amplitude + LDS scatter ----
    const int idx = (ep * 64 + (ex >> 1)) * 64 + (ey >> 1);
    const bool touch = gate && (t <= nr);
    if (touch) {
        float a = -GMIN;
        if (amb) {
            for (int i = 0; i < nA; ++i) {
                unsigned e = lpk[i];
                if ((e & 0xFFFFu) == key && (e >> 16) < (unsigned)t)
                    a = ((e >> 16) == 0u)
                            ? (PFRAC * (GMAX - GMIN) - GMIN)   // init SETs 0.27
                            : fmaf(1.0f - PFRAC, a, lCr[i]);
            }
        }
        a = (t == 0) ? (PFRAC * (GMAX - GMIN) - GMIN)
                     : fmaf(1.0f - PFRAC, a, myCr);
        float val = fmaf(C_r, a, GMIN);                 // >= u_r >= 0
        atomicMax(&tile[idx], __float_as_int(val));
    }
    __syncthreads();   // vmcnt(0): plane fill committed; tile final

    // ---- P5: sparse patch of touched cells (benign same-value races) ----
    if (touch) {
        int* oi = reinterpret_cast<int*>(out) + (size_t)(s * 8 + r) * 8192;
        oi[idx] = tile[idx];
    }
}

extern "C" void kernel_launch(void* const* d_in, const int* in_sizes, int n_in,
                              void* d_out, int out_size, void* d_ws, size_t ws_size,
                              hipStream_t stream) {
    const int*   event  = (const int*)  d_in[0];
    const float* ts     = (const float*)d_in[1];
    const int*   tt     = (const int*)  d_in[2];
    const int*   length = (const int*)  d_in[3];
    float*       out    = (float*)d_out;

    // 128 samples x 8 slots = 1024 blocks x 512 threads
    fuse_kernel<<<dim3(SN * 8), dim3(512), 0, stream>>>(event, ts, tt, length, out);
}

// Round 24
// 16.983 us; speedup vs baseline: 1.1072x; 1.1072x over previous
//
#include <hip/hip_runtime.h>

#define SN 128
#define SPK 512

constexpr float GMIN  = 0.1f;
constexpr float PFRAC = 0.3f;
constexpr float GMAX  = 1.0f;

// LDS-composed output tile, single global writeout (best variant, R22).
// Lazy decay: v(n) = C(n)*a + GMIN, C(n) = exp((ts0-ts[n])/TAU) <= 1.
// Untouched cell at snapshot r: u_r = GMIN*(1-C_r) (identical everywhere).
// Touch at n: a' = (1-PFRAC)*a + PFRAC*(GMAX-GMIN)/C(n); amplitude is
// non-decreasing over the touch prefix -> per-touch own-prefix candidates +
// max reproduce the exact final value (verified absmax 0.0, R11/R17-R23).
// Same-cell predecessors: hash-count buckets; only events in buckets with
// count>=2 are compacted (time order) and scanned (no false negatives).
// Per-slot snlast via one ballot per wave + 8-entry reduce (no LDS atomics).
//
// Block = (s, r): one output plane (2 pol x 64 x 64 = 32 KB) built in LDS:
// memset to u_r -> LDS atomicMax scatter -> coalesced 32 KB writeout.
// Single writeout keeps HBM write traffic at the irreducible 33.5 MB
// (fill-then-patch doubles it via L2 evictions -- R23 regression).

__global__ __launch_bounds__(512, 4) void fuse_kernel(
    const int*   __restrict__ event,   // (SN, SPK, 3) int32: x, y, pol
    const float* __restrict__ ts,      // (SN, SPK) f32, ascending
    const int*   __restrict__ tt,      // (SN, SPK) int32 in [0,8)
    const int*   __restrict__ length,  // (SN,) int32
    float*       __restrict__ out)     // (SN, 8, 2, 64, 64) f32
{
    __shared__ int      tile[2 * 64 * 64];   // 32 KB; first 16 KB aliased as hcnt
    __shared__ float    stsn[SPK];
    __shared__ unsigned lpk [SPK];           // ambiguous list: (n<<16)|key
    __shared__ float    lCr [SPK];
    __shared__ int      wlast[8];            // per-wave last occurrence of slot r
    __shared__ int      wcnt [8];
    __shared__ float    sCs;                 // C_r
    __shared__ int      sNr;                 // n_r
    __shared__ int      sUb;                 // bits(u_r)

    unsigned* hcnt = (unsigned*)tile;        // 4096 buckets (dead after P2)

    const int blk  = blockIdx.x;
    const int s    = blk >> 3;
    const int r    = blk & 7;
    const int t    = threadIdx.x;            // event index n = t
    const int lane = t & 63;
    const int wid  = t >> 6;                 // 0..7

    const int   len = length[s];
    const float ts0 = ts[s * SPK];

    // issue event loads early
    const int* ev = event + (size_t)(s * SPK + t) * 3;
    const int   ex  = ev[0], ey = ev[1], ep = ev[2];
    const float tsn = ts[s * SPK + t];
    const int   tv  = tt[s * SPK + t];

    // ---- P0: init hash buckets ----
#pragma unroll
    for (int k = 0; k < 8; ++k) hcnt[t + k * 512] = 0u;
    __syncthreads();

    // ---- P1: stage + hash count + per-wave snlast ballot ----
    const bool     gate = (t < len);                    // t==0 always (len>=1)
    const unsigned key  = (unsigned)((ep << 14) | (ex << 7) | ey);
    const float    myCr = (PFRAC * (GMAX - GMIN)) * __expf(-(ts0 - tsn) * 0.01f);
    const unsigned h    = (key * 2654435761u) >> 20;    // 12-bit bucket
    stsn[t] = tsn;
    if (gate) atomicAdd(&hcnt[h], 1u);
    {
        unsigned long long m = __ballot(t >= 1 && tv == r);
        if (lane == 0)
            wlast[wid] = m ? (wid * 64 + 63 - (int)__clzll(m)) : -1;
    }
    __syncthreads();

    // ---- P2: slot table (thread 0) + ambiguity flags (all hcnt reads) ----
    if (t == 0) {
        int nr = wlast[0];
#pragma unroll
        for (int w = 1; w < 8; ++w) nr = max(nr, wlast[w]);
        if (r == 0 && nr < 0) nr = 0;                   // slot0 -> init state
        float C = 0.0f;
        if (nr >= 0) C = __expf((ts0 - stsn[nr]) * 0.01f);   // C_r <= 1
        sNr = nr;
        sCs = C;
        sUb = __float_as_int((nr >= 0) ? (GMIN - C * GMIN) : 0.0f);
    }
    const bool amb = gate && (hcnt[h] > 1u);
    const unsigned long long bm = __ballot(amb);
    if (lane == 0) wcnt[wid] = (int)__popcll(bm);
    __syncthreads();                                    // hcnt dead from here

    // ---- P3: compact ambiguous (time order) + tile memset to u_r ----
    int base = 0, nA = 0;
#pragma unroll
    for (int w = 0; w < 8; ++w) {
        int c = wcnt[w];
        if (w < wid) base += c;
        nA += c;
    }
    if (amb) {
        int pos = base + (int)__popcll(bm & ((1ull << lane) - 1ull));
        lpk[pos] = ((unsigned)t << 16) | key;
        lCr[pos] = myCr;
    }
    const int   nr  = sNr;
    const float C_r = sCs;
    {
        int4 u4; u4.x = u4.y = u4.z = u4.w = sUb;
        int4* T = (int4*)tile;
#pragma unroll
        for (int k = 0; k < 4; ++k) T[t + k * 512] = u4;
    }
    __syncthreads();                                    // tile + lpk/lCr ready

    // ---- P4: own-prefix amplitude + LDS scatter ----
    if (gate && t <= nr) {
        float a = -GMIN;
        if (amb) {
            for (int i = 0; i < nA; ++i) {
                unsigned e = lpk[i];
                if ((e & 0xFFFFu) == key && (e >> 16) < (unsigned)t)
                    a = ((e >> 16) == 0u)
                            ? (PFRAC * (GMAX - GMIN) - GMIN)   // init SETs 0.27
                            : fmaf(1.0f - PFRAC, a, lCr[i]);
            }
        }
        a = (t == 0) ? (PFRAC * (GMAX - GMIN) - GMIN)
                     : fmaf(1.0f - PFRAC, a, myCr);
        float val = fmaf(C_r, a, GMIN);                 // >= u_r >= 0
        int   idx = (ep * 64 + (ex >> 1)) * 64 + (ey >> 1);
        atomicMax(&tile[idx], __float_as_int(val));
    }
    __syncthreads();

    // ---- P5: single coalesced writeout (2048 float4) ----
    float4*       o4 = reinterpret_cast<float4*>(out + (size_t)(s * 8 + r) * 8192);
    const float4* t4 = reinterpret_cast<const float4*>(tile);
#pragma unroll
    for (int k = 0; k < 4; ++k) o4[t + k * 512] = t4[t + k * 512];
}

extern "C" void kernel_launch(void* const* d_in, const int* in_sizes, int n_in,
                              void* d_out, int out_size, void* d_ws, size_t ws_size,
                              hipStream_t stream) {
    const int*   event  = (const int*)  d_in[0];
    const float* ts     = (const float*)d_in[1];
    const int*   tt     = (const int*)  d_in[2];
    const int*   length = (const int*)  d_in[3];
    float*       out    = (float*)d_out;

    // 128 samples x 8 slots = 1024 blocks x 512 threads
    fuse_kernel<<<dim3(SN * 8), dim3(512), 0, stream>>>(event, ts, tt, length, out);
}